// Round 15
// baseline (128.815 us; speedup 1.0000x reference)
//
#include <hip/hip_runtime.h>
#include <hip/hip_bf16.h>
#include <math.h>

// MMD (InfoVAE RBF kernel), N=8192, D=128, fp32 in, scalar fp32 out.
//
// Round 15: r14 + look-ahead double-buffered staging.
//   Two 32 KB phase buffers: DMA(p0) -> barrier (only exposed drain) ->
//   DMA(p1) issue -> compute p0 -> barrier (DMA1 had all of p0's compute to
//   land -> ~free drain) -> compute p1. LDS 67 KB -> 2 blocks/CU
//   (launch_bounds(256,2)). Loop body/registers identical to r14 (the r12
//   spill came from two-tile bookkeeping, absent here). Phase rows stay
//   128 B (half-K): the minimum conflict-free width for XOR-swizzled
//   ds_read_b128 (64-B rows alias 4-way -> r12's 4.2M conflicts).
//   Known-toxic (measured): fused finish w/ per-block __threadfence (r13:
//   L2 invalidate thrash, 3.4x), per-wave B-from-L2 (r11), quarter-K rows
//   (r12), DMA builtin imm offset != 0 (r8/r9: applies LDS-side).
//   - Unified Z = [X;Y]: MMD*N^2 = sum s_i s_j k(z_i,z_j); upper-triangle
//     128x128 tiles (8256), uniform +-1/+-2 tile weights.
//   Numerics (r3-r14): bf16 MFMA arg noise zero-mean -> ~2e-9 MMD shift;
//   exp2 HW bias cancels in +1+1-2; fp32 per-tile partials (<=16); fp64
//   across blocks. absmax 5.96e-8 stable (threshold 7.15e-8).

#define NN 8192
#define DD 128
#define TZ 16384
#define TILES 128
#define NBLOCKS (TILES * (TILES + 1) / 2)   // 8256

typedef __attribute__((ext_vector_type(8))) short bf16x8;
typedef __attribute__((ext_vector_type(4))) float f32x4;
typedef __attribute__((ext_vector_type(2))) float f32x2;

#if __has_builtin(__builtin_amdgcn_exp2f)
#define EXP2F __builtin_amdgcn_exp2f
#else
#define EXP2F exp2f
#endif

constexpr float LOG2E = 0x1.715476p+0f;
constexpr float S2 = LOG2E / 8192.0f;              // 2*log2e/16384

constexpr int PANEL = 16384;                       // 128 rows x 128 B (half-K panel)
constexpr int PBUF  = 2 * PANEL;                   // one phase buffer: A+B panels

// ---- ws layout ----
constexpr size_t WS_NORM = 768;
constexpr size_t WS_Z    = WS_NORM + (size_t)TZ * sizeof(float);

__device__ __forceinline__ void gload_lds16(const void* g, void* l) {
  __builtin_amdgcn_global_load_lds(
      (const __attribute__((address_space(1))) void*)g,
      (__attribute__((address_space(3))) void*)l, 16, 0, 0);
}

__global__ __launch_bounds__(256) void prep(
    const float* __restrict__ X, const float* __restrict__ Y,
    __hip_bfloat16* __restrict__ Z, float* __restrict__ normZ,
    double* __restrict__ sums) {
  if (blockIdx.x == 0 && threadIdx.x < 64) sums[threadIdx.x] = 0.0;

  const int row = blockIdx.x * 4 + (threadIdx.x >> 6);
  const int lane = threadIdx.x & 63;
  const float* __restrict__ src =
      (row < NN) ? (X + (size_t)row * DD) : (Y + (size_t)(row - NN) * DD);
  const float2 v = *reinterpret_cast<const float2*>(src + 2 * lane);

  float n = v.x * v.x + v.y * v.y;
  *reinterpret_cast<__hip_bfloat162*>(Z + (size_t)row * DD + 2 * lane) =
      __hip_bfloat162{__float2bfloat16(v.x), __float2bfloat16(v.y)};

#pragma unroll
  for (int o = 32; o > 0; o >>= 1) n += __shfl_down(n, o);
  if (lane == 0) normZ[row] = n * (-LOG2E / 16384.0f);  // pre-scaled
}

__device__ __forceinline__ int tri_start(int i) {
  return i * TILES - (i * (i - 1)) / 2;
}

__global__ __launch_bounds__(256, 2) void mmd_mfma(
    const __hip_bfloat16* __restrict__ Z, const float* __restrict__ normZ,
    double* __restrict__ sums) {
  __shared__ alignas(16) char lds[2 * PBUF + 1024];  // two phase buffers + pad
  __shared__ float rowN[128], colN[128];
  __shared__ double red[4];

  const int t = blockIdx.x;
  int I = (int)((257.0 - sqrt(257.0 * 257.0 - 8.0 * (double)t)) * 0.5);
  if (I > 127) I = 127;
  if (I < 0) I = 0;
  while (I < 127 && tri_start(I + 1) <= t) ++I;
  while (I > 0 && tri_start(I) > t) --I;
  const int J = I + (t - tri_start(I));

  const int tid = threadIdx.x;
  const int lane = tid & 63, wave = tid >> 6;
  const int wr = wave >> 1, wc = wave & 1;       // 2x2 wave grid over 128x128
  const int lr = lane & 15, quad = lane >> 4;    // MFMA lane decomposition

  if (tid < 128) rowN[tid] = normZ[I * 128 + tid];
  else           colN[tid - 128] = normZ[J * 128 + tid - 128];

  // Staging: lane of wave w, issue l covers row = 8w + (lane>>3) + 32l,
  // LDS chunk c = lane&7 holds global chunk g = c ^ (row&7) (l-invariant).
  // Each global row is 256 B; phase p selects the 128-B half via +p*128
  // folded into the global pointer (NO builtin offset arg - r8/r9).
  const char* Zb = (const char*)Z;
  const int r5 = tid >> 3;                       // 0..31
  const int g = (tid & 7) ^ (r5 & 7);
  const char* gA = Zb + (size_t)I * 32768 + r5 * 256 + g * 16;
  const char* gB = Zb + (size_t)J * 32768 + r5 * 256 + g * 16;
  char* lw = lds + wave * 1024;                  // wave-uniform LDS base

  // MFMA LDS read bases (swizzled chunk: (ks*4+quad) ^ (lr&7), bits disjoint).
  const int aBase = (wr * 64 + lr) * 128;
  const int bBase = PANEL + (wc * 64 + lr) * 128;
  const int sa = lr & 7;

  // --- Issue phase-0 DMA into buffer 0 ---
#pragma unroll
  for (int l = 0; l < 4; ++l) {
    gload_lds16(gA + l * 8192, lw + l * 4096);
    gload_lds16(gB + l * 8192, lw + PANEL + l * 4096);
  }
  __syncthreads();  // drain DMA0 (the only exposed drain); publishes rowN/colN

  // --- Issue phase-1 DMA into buffer 1 (in flight during p0 compute) ---
#pragma unroll
  for (int l = 0; l < 4; ++l) {
    gload_lds16(gA + 128 + l * 8192, lw + PBUF + l * 4096);
    gload_lds16(gB + 128 + l * 8192, lw + PBUF + PANEL + l * 4096);
  }

  f32x4 acc[4][4] = {};
#pragma unroll
  for (int p = 0; p < 2; ++p) {
    const char* buf = lds + p * PBUF;
#pragma unroll
    for (int ks = 0; ks < 2; ++ks) {
      const int csw = (((ks * 4) + quad) ^ sa) * 16;
      bf16x8 a[4], b[4];
#pragma unroll
      for (int i = 0; i < 4; ++i) {
        a[i] = *reinterpret_cast<const bf16x8*>(buf + aBase + i * 2048 + csw);
        b[i] = *reinterpret_cast<const bf16x8*>(buf + bBase + i * 2048 + csw);
      }
#pragma unroll
      for (int i = 0; i < 4; ++i)
#pragma unroll
        for (int j = 0; j < 4; ++j)
          acc[i][j] = __builtin_amdgcn_mfma_f32_16x16x32_bf16(a[i], b[j], acc[i][j], 0, 0, 0);
    }
    if (p == 0) __syncthreads();  // drain DMA1 (~free: p0 compute covered it)
  }

  // Epilogue (C/D: col=lane&15, row=quad*4+reg), packed fp32 pairs:
  // k = exp2(acc*S2 + ra + rb), ra/rb pre-scaled by -log2e/16384.
  const f32x2 s2v = {S2, S2};
  f32x2 part01 = {0.f, 0.f}, part23 = {0.f, 0.f};
#pragma unroll
  for (int i = 0; i < 4; ++i) {
    const int rbase = wr * 64 + i * 16 + quad * 4;
    const f32x2 ar01 = {rowN[rbase + 0], rowN[rbase + 1]};
    const f32x2 ar23 = {rowN[rbase + 2], rowN[rbase + 3]};
#pragma unroll
    for (int j = 0; j < 4; ++j) {
      const float rb = colN[wc * 64 + j * 16 + lr];
      const f32x2 rb2 = {rb, rb};
      const f32x2 base01 = ar01 + rb2;
      const f32x2 base23 = ar23 + rb2;
      const f32x2 acc01 = {acc[i][j][0], acc[i][j][1]};
      const f32x2 acc23 = {acc[i][j][2], acc[i][j][3]};
      const f32x2 arg01 = __builtin_elementwise_fma(acc01, s2v, base01);
      const f32x2 arg23 = __builtin_elementwise_fma(acc23, s2v, base23);
      part01 += (f32x2){EXP2F(arg01.x), EXP2F(arg01.y)};
      part23 += (f32x2){EXP2F(arg23.x), EXP2F(arg23.y)};
    }
  }
  const f32x2 ps = part01 + part23;
  double local = (double)(ps.x + ps.y);
  double w = ((I < 64) == (J < 64)) ? 1.0 : -1.0;
  if (I != J) w += w;
  local *= w;

#pragma unroll
  for (int o = 32; o > 0; o >>= 1) local += __shfl_down(local, o);
  if (lane == 0) red[wave] = local;
  __syncthreads();
  if (tid == 0) atomicAdd(&sums[t & 63], red[0] + red[1] + red[2] + red[3]);
}

__global__ void finish(const double* __restrict__ s, float* __restrict__ out) {
  double v = s[threadIdx.x];
#pragma unroll
  for (int o = 32; o > 0; o >>= 1) v += __shfl_down(v, o);
  if (threadIdx.x == 0)
    out[0] = (float)(v * (1.0 / ((double)NN * (double)NN)));
}

extern "C" void kernel_launch(void* const* d_in, const int* in_sizes, int n_in,
                              void* d_out, int out_size, void* d_ws, size_t ws_size,
                              hipStream_t stream) {
  const float* y_inputs = (const float*)d_in[0];  // "inputs"
  const float* x_true   = (const float*)d_in[1];  // "true_samples"
  float* out = (float*)d_out;

  char* ws = (char*)d_ws;
  double* sums = (double*)ws;                     // 64 fp64 partial slots
  float* normZ = (float*)(ws + WS_NORM);
  __hip_bfloat16* Z = (__hip_bfloat16*)(ws + WS_Z);

  prep<<<TZ / 4, 256, 0, stream>>>(x_true, y_inputs, Z, normZ, sums);
  mmd_mfma<<<NBLOCKS, 256, 0, stream>>>(Z, normZ, sums);
  finish<<<1, 64, 0, stream>>>(sums, out);
}